// Round 1
// baseline (854.835 us; speedup 1.0000x reference)
//
#include <hip/hip_runtime.h>

#define N_NODES 100000
#define N_EDGES 3200000
#define F_IN    128
#define HID     64
#define NGRAPH  64
#define L1CAP   262144
#define L2CAP   32768

__device__ __forceinline__ bool is_big(int v, const int* __restrict__ batch) {
    return (v == N_NODES - 1) || (batch[v] != batch[v + 1]);
}

// needed[v] = 1 if v is the last node of its graph, else 0 (full init, no memset needed)
__global__ void k_init(const int* __restrict__ batch, int* __restrict__ needed) {
    int v = blockIdx.x * 256 + threadIdx.x;
    if (v >= N_NODES) return;
    needed[v] = is_big(v, batch) ? 1 : 0;
}

// deg[v] = # edges with dst==v  (self-loop added later as +1)
__global__ void k_deg(const int* __restrict__ dst, int* __restrict__ deg) {
    int e = blockIdx.x * 256 + threadIdx.x;
    if (e >= N_EDGES) return;
    atomicAdd(&deg[dst[e]], 1);
}

// edges into big nodes: mark their sources as needed, compact into l2list
__global__ void k_mark(const int* __restrict__ src, const int* __restrict__ dst,
                       const int* __restrict__ batch, int* __restrict__ needed,
                       int2* __restrict__ l2list, int* __restrict__ counters) {
    int e = blockIdx.x * 256 + threadIdx.x;
    if (e >= N_EDGES) return;
    int v = dst[e];
    if (is_big(v, batch)) {
        int u = src[e];
        needed[u] = 1;
        int p = atomicAdd(&counters[1], 1);
        if (p < L2CAP) l2list[p] = make_int2(u, v);
    }
}

// edges into needed nodes: compact into l1list
__global__ void k_compact1(const int* __restrict__ src, const int* __restrict__ dst,
                           const int* __restrict__ needed,
                           int2* __restrict__ l1list, int* __restrict__ counters) {
    int e = blockIdx.x * 256 + threadIdx.x;
    if (e >= N_EDGES) return;
    int v = dst[e];
    if (needed[v]) {
        int p = atomicAdd(&counters[0], 1);
        if (p < L1CAP) l1list[p] = make_int2(src[e], v);
    }
}

__global__ void k_dinv(const int* __restrict__ deg, float* __restrict__ dinv) {
    int v = blockIdx.x * 256 + threadIdx.x;
    if (v >= N_NODES) return;
    dinv[v] = rsqrtf((float)(deg[v] + 1));   // +1 self-loop; always > 0
}

// h_pre = x @ W1   (N x 128 @ 128 x 64). W1 in LDS; wave = one row, lane = feature.
__global__ __launch_bounds__(256) void k_gemm(const float* __restrict__ x,
                                              const float* __restrict__ W1,
                                              float* __restrict__ h_pre) {
    __shared__ float Wl[F_IN * HID];   // 32 KiB
    for (int i = threadIdx.x; i < F_IN * HID; i += 256) Wl[i] = W1[i];
    __syncthreads();
    int wave = threadIdx.x >> 6;
    int f    = threadIdx.x & 63;
    int v    = blockIdx.x * 4 + wave;
    if (v >= N_NODES) return;
    const float4* xr = (const float4*)(x + (size_t)v * F_IN);
    float acc = 0.f;
#pragma unroll
    for (int k4 = 0; k4 < F_IN / 4; ++k4) {
        float4 xa = xr[k4];           // broadcast within wave (same addr, 1 txn)
        int k = k4 * 4;
        acc += xa.x * Wl[(k + 0) * HID + f];
        acc += xa.y * Wl[(k + 1) * HID + f];
        acc += xa.z * Wl[(k + 2) * HID + f];
        acc += xa.w * Wl[(k + 3) * HID + f];
    }
    h_pre[(size_t)v * HID + f] = acc;
}

// layer-1 aggregation over compacted edges: wave per edge, lane = feature
__global__ void k_agg1(const int2* __restrict__ l1list, const int* __restrict__ counters,
                       const float* __restrict__ dinv, const float* __restrict__ h_pre,
                       float* __restrict__ agg1) {
    int wid = (blockIdx.x * 256 + threadIdx.x) >> 6;
    int nw  = (gridDim.x * 256) >> 6;
    int f   = threadIdx.x & 63;
    int n   = counters[0];
    if (n > L1CAP) n = L1CAP;
    for (int i = wid; i < n; i += nw) {
        int2 e = l1list[i];
        float w = dinv[e.x] * dinv[e.y];
        atomicAdd(&agg1[(size_t)e.y * HID + f], w * h_pre[(size_t)e.x * HID + f]);
    }
}

// per needed node: self-loop + bias + relu, then dot with W2 -> h2s[v]
__global__ void k_node2(const int* __restrict__ needed, const float* __restrict__ agg1,
                        const float* __restrict__ h_pre, const float* __restrict__ dinv,
                        const float* __restrict__ b1, const float* __restrict__ W2,
                        float* __restrict__ h2s) {
    int v = (blockIdx.x * 256 + threadIdx.x) >> 6;
    int f = threadIdx.x & 63;
    if (v >= N_NODES) return;
    if (!needed[v]) return;                      // wave-uniform branch
    float di  = dinv[v];
    float val = agg1[(size_t)v * HID + f] + di * di * h_pre[(size_t)v * HID + f] + b1[f];
    val = fmaxf(val, 0.f);
    float c = val * W2[f];
#pragma unroll
    for (int off = 32; off > 0; off >>= 1) c += __shfl_down(c, off, 64);
    if (f == 0) h2s[v] = c;
}

// layer-2 aggregation over the ~2k big-dst edges
__global__ void k_agg2(const int2* __restrict__ l2list, const int* __restrict__ counters,
                       const float* __restrict__ dinv, const float* __restrict__ h2s,
                       const int* __restrict__ batch, float* __restrict__ out) {
    int tid = blockIdx.x * 256 + threadIdx.x;
    int nt  = gridDim.x * 256;
    int n   = counters[1];
    if (n > L2CAP) n = L2CAP;
    for (int i = tid; i < n; i += nt) {
        int2 e = l2list[i];
        atomicAdd(&out[batch[e.y]], dinv[e.x] * dinv[e.y] * h2s[e.x]);
    }
}

// self-loop term + b2 for each big node (exactly one per graph; runs after k_agg2)
__global__ void k_final(const int* __restrict__ batch, const float* __restrict__ dinv,
                        const float* __restrict__ h2s, const float* __restrict__ b2,
                        float* __restrict__ out) {
    int v = blockIdx.x * 256 + threadIdx.x;
    if (v >= N_NODES) return;
    if (is_big(v, batch)) {
        float di = dinv[v];
        out[batch[v]] += di * di * h2s[v] + b2[0];
    }
}

extern "C" void kernel_launch(void* const* d_in, const int* in_sizes, int n_in,
                              void* d_out, int out_size, void* d_ws, size_t ws_size,
                              hipStream_t stream) {
    const float* x     = (const float*)d_in[0];
    const int*   eidx  = (const int*)d_in[1];
    const int*   src   = eidx;
    const int*   dst   = eidx + N_EDGES;
    const int*   batch = (const int*)d_in[2];
    const float* W1    = (const float*)d_in[3];
    const float* b1    = (const float*)d_in[4];
    const float* W2    = (const float*)d_in[5];
    const float* b2    = (const float*)d_in[6];
    float*       out   = (float*)d_out;

    // ---- workspace layout (zeroed region first: agg1 | deg | counters) ----
    char* ws = (char*)d_ws;
    size_t off = 0;
    float* agg1     = (float*)(ws + off); off += (size_t)N_NODES * HID * 4; // 25.6 MB
    int*   deg      = (int*)  (ws + off); off += (size_t)N_NODES * 4;       // 0.4 MB
    int*   counters = (int*)  (ws + off); off += 256;
    size_t zero_bytes = off;
    float* h_pre    = (float*)(ws + off); off += (size_t)N_NODES * HID * 4; // 25.6 MB
    float* dinv     = (float*)(ws + off); off += (size_t)N_NODES * 4;
    float* h2s      = (float*)(ws + off); off += (size_t)N_NODES * 4;
    int*   needed   = (int*)  (ws + off); off += (size_t)N_NODES * 4;
    int2*  l1list   = (int2*) (ws + off); off += (size_t)L1CAP * 8;
    int2*  l2list   = (int2*) (ws + off); off += (size_t)L2CAP * 8;
    if (off > ws_size) return;  // ws too small -> visible validation failure

    hipMemsetAsync(d_ws, 0, zero_bytes, stream);
    hipMemsetAsync(d_out, 0, (size_t)out_size * 4, stream);

    const int BN = (N_NODES + 255) / 256;   // node-grid
    const int BE = (N_EDGES + 255) / 256;   // edge-grid

    k_init<<<BN, 256, 0, stream>>>(batch, needed);
    k_deg<<<BE, 256, 0, stream>>>(dst, deg);
    k_mark<<<BE, 256, 0, stream>>>(src, dst, batch, needed, l2list, counters);
    k_compact1<<<BE, 256, 0, stream>>>(src, dst, needed, l1list, counters);
    k_dinv<<<BN, 256, 0, stream>>>(deg, dinv);
    k_gemm<<<(N_NODES + 3) / 4, 256, 0, stream>>>(x, W1, h_pre);
    k_agg1<<<1024, 256, 0, stream>>>(l1list, counters, dinv, h_pre, agg1);
    k_node2<<<(N_NODES * 64 + 255) / 256, 256, 0, stream>>>(needed, agg1, h_pre, dinv, b1, W2, h2s);
    k_agg2<<<32, 256, 0, stream>>>(l2list, counters, dinv, h2s, batch, out);
    k_final<<<BN, 256, 0, stream>>>(batch, dinv, h2s, b2, out);
}

// Round 2
// 424.446 us; speedup vs baseline: 2.0140x; 2.0140x over previous
//
#include <hip/hip_runtime.h>

#define N_NODES 100000
#define N_EDGES 3200000
#define F_IN    128
#define HID     64
#define NGRAPH  64
#define L1CAP   262144
#define L2CAP   32768
#define NLCAP   16384

// counters: [0]=l1 edge count, [1]=l2 edge count, [2]=needed-node count

__device__ __forceinline__ bool is_big(int v, const int* __restrict__ batch) {
    return (v == N_NODES - 1) || (batch[v] != batch[v + 1]);
}

// needed[v] = 1 iff big node; big nodes appended to nlist (so nlist[0..63] = big nodes)
__global__ void k_init(const int* __restrict__ batch, int* __restrict__ needed,
                       int* __restrict__ nlist, int* __restrict__ counters) {
    int v = blockIdx.x * 256 + threadIdx.x;
    if (v >= N_NODES) return;
    bool big = is_big(v, batch);
    needed[v] = big ? 1 : 0;
    if (big) {
        int p = atomicAdd(&counters[2], 1);   // only 64 of these
        if (p < NLCAP) nlist[p] = v;
    }
}

// Fused: deg histogram + big-dst edge detection (l2 list, needed marking, nlist append).
// l2 appends buffered in LDS, one global counter atomic per flush.
__global__ __launch_bounds__(256) void k_degmark(const int* __restrict__ src,
        const int* __restrict__ dst, const int* __restrict__ batch,
        int* __restrict__ deg, int* __restrict__ needed, int* __restrict__ nlist,
        int2* __restrict__ l2list, int* __restrict__ counters) {
    __shared__ int2 buf[512];
    __shared__ int scount, sbase;
    if (threadIdx.x == 0) scount = 0;
    __syncthreads();
    for (int e0 = blockIdx.x * 256; e0 < N_EDGES; e0 += gridDim.x * 256) {
        int e = e0 + threadIdx.x;
        bool hit = false; int u = 0, v = 0;
        if (e < N_EDGES) {
            v = dst[e];
            atomicAdd(&deg[v], 1);
            if (is_big(v, batch)) {
                u = src[e];
                hit = true;
                if (atomicExch(&needed[u], 1) == 0) {     // dedup: append once
                    int p = atomicAdd(&counters[2], 1);   // ~2k total, ok
                    if (p < NLCAP) nlist[p] = u;
                }
            }
        }
        if (hit) {
            int p = atomicAdd(&scount, 1);                // LDS atomic, cheap
            if (p < 512) buf[p] = make_int2(u, v);
        }
        __syncthreads();                                   // appends visible
        if (scount > 512 - 256) {                          // uniform: flush
            if (threadIdx.x == 0) sbase = atomicAdd(&counters[1], scount);
            __syncthreads();
            for (int i = threadIdx.x; i < scount; i += 256) {
                int p = sbase + i;
                if (p < L2CAP) l2list[p] = buf[i];
            }
            __syncthreads();
            if (threadIdx.x == 0) scount = 0;
        }
        __syncthreads();
    }
    if (scount > 0) {                                      // final flush
        if (threadIdx.x == 0) sbase = atomicAdd(&counters[1], scount);
        __syncthreads();
        for (int i = threadIdx.x; i < scount; i += 256) {
            int p = sbase + i;
            if (p < L2CAP) l2list[p] = buf[i];
        }
    }
}

// Edges into needed nodes -> l1list, LDS-buffered (one counter atomic per flush)
__global__ __launch_bounds__(256) void k_compact1(const int* __restrict__ src,
        const int* __restrict__ dst, const int* __restrict__ needed,
        int2* __restrict__ l1list, int* __restrict__ counters) {
    __shared__ int2 buf[1024];
    __shared__ int scount, sbase;
    if (threadIdx.x == 0) scount = 0;
    __syncthreads();
    for (int e0 = blockIdx.x * 256; e0 < N_EDGES; e0 += gridDim.x * 256) {
        int e = e0 + threadIdx.x;
        bool hit = false; int u = 0, v = 0;
        if (e < N_EDGES) {
            v = dst[e];
            if (needed[v]) { u = src[e]; hit = true; }
        }
        if (hit) {
            int p = atomicAdd(&scount, 1);
            if (p < 1024) buf[p] = make_int2(u, v);
        }
        __syncthreads();
        if (scount > 1024 - 256) {
            if (threadIdx.x == 0) sbase = atomicAdd(&counters[0], scount);
            __syncthreads();
            for (int i = threadIdx.x; i < scount; i += 256) {
                int p = sbase + i;
                if (p < L1CAP) l1list[p] = buf[i];
            }
            __syncthreads();
            if (threadIdx.x == 0) scount = 0;
        }
        __syncthreads();
    }
    if (scount > 0) {
        if (threadIdx.x == 0) sbase = atomicAdd(&counters[0], scount);
        __syncthreads();
        for (int i = threadIdx.x; i < scount; i += 256) {
            int p = sbase + i;
            if (p < L1CAP) l1list[p] = buf[i];
        }
    }
}

__global__ void k_dinv(const int* __restrict__ deg, float* __restrict__ dinv) {
    int v = blockIdx.x * 256 + threadIdx.x;
    if (v >= N_NODES) return;
    dinv[v] = rsqrtf((float)(deg[v] + 1));   // +1 self-loop
}

// h_pre = x @ W1 (N x 128 @ 128 x 64). W1 in LDS; wave = row, lane = feature.
// Grid-stride so W1's LDS load amortizes over ~12 row-groups per block.
__global__ __launch_bounds__(256) void k_gemm(const float* __restrict__ x,
                                              const float* __restrict__ W1,
                                              float* __restrict__ h_pre) {
    __shared__ float Wl[F_IN * HID];   // 32 KiB
    for (int i = threadIdx.x; i < F_IN * HID; i += 256) Wl[i] = W1[i];
    __syncthreads();
    int wave = threadIdx.x >> 6;
    int f    = threadIdx.x & 63;
    for (int v0 = blockIdx.x * 4; v0 < N_NODES; v0 += gridDim.x * 4) {
        int v = v0 + wave;
        if (v >= N_NODES) continue;
        const float4* xr = (const float4*)(x + (size_t)v * F_IN);
        float acc = 0.f;
#pragma unroll
        for (int k4 = 0; k4 < F_IN / 4; ++k4) {
            float4 xa = xr[k4];           // wave-broadcast load
            int k = k4 * 4;
            acc += xa.x * Wl[(k + 0) * HID + f];   // bank = f%32: 2-way, free
            acc += xa.y * Wl[(k + 1) * HID + f];
            acc += xa.z * Wl[(k + 2) * HID + f];
            acc += xa.w * Wl[(k + 3) * HID + f];
        }
        h_pre[(size_t)v * HID + f] = acc;
    }
}

// layer-1 aggregation over compacted edges: wave per edge, lane = feature
__global__ void k_agg1(const int2* __restrict__ l1list, const int* __restrict__ counters,
                       const float* __restrict__ dinv, const float* __restrict__ h_pre,
                       float* __restrict__ agg1) {
    int wid = (blockIdx.x * 256 + threadIdx.x) >> 6;
    int nw  = (gridDim.x * 256) >> 6;
    int f   = threadIdx.x & 63;
    int n   = counters[0];
    if (n > L1CAP) n = L1CAP;
    for (int i = wid; i < n; i += nw) {
        int2 e = l1list[i];
        float w = dinv[e.x] * dinv[e.y];
        atomicAdd(&agg1[(size_t)e.y * HID + f], w * h_pre[(size_t)e.x * HID + f]);
    }
}

// per needed node (via compact nlist): self-loop + bias + relu, dot W2 -> h2s[v]
__global__ void k_node2(const int* __restrict__ nlist, const int* __restrict__ counters,
                        const float* __restrict__ agg1, const float* __restrict__ h_pre,
                        const float* __restrict__ dinv, const float* __restrict__ b1,
                        const float* __restrict__ W2, float* __restrict__ h2s) {
    int wid = (blockIdx.x * 256 + threadIdx.x) >> 6;
    int nw  = (gridDim.x * 256) >> 6;
    int f   = threadIdx.x & 63;
    int n   = counters[2];
    if (n > NLCAP) n = NLCAP;
    for (int i = wid; i < n; i += nw) {
        int v = nlist[i];
        float di  = dinv[v];
        float val = agg1[(size_t)v * HID + f] + di * di * h_pre[(size_t)v * HID + f] + b1[f];
        val = fmaxf(val, 0.f);
        float c = val * W2[f];
#pragma unroll
        for (int off = 32; off > 0; off >>= 1) c += __shfl_down(c, off, 64);
        if (f == 0) h2s[v] = c;
    }
}

// layer-2 aggregation over the ~2k big-dst edges
__global__ void k_agg2(const int2* __restrict__ l2list, const int* __restrict__ counters,
                       const float* __restrict__ dinv, const float* __restrict__ h2s,
                       const int* __restrict__ batch, float* __restrict__ out) {
    int tid = blockIdx.x * 256 + threadIdx.x;
    int nt  = gridDim.x * 256;
    int n   = counters[1];
    if (n > L2CAP) n = L2CAP;
    for (int i = tid; i < n; i += nt) {
        int2 e = l2list[i];
        atomicAdd(&out[batch[e.y]], dinv[e.x] * dinv[e.y] * h2s[e.x]);
    }
}

// self-loop + b2 per big node; nlist[0..63] are exactly the big nodes (k_init order)
__global__ void k_final(const int* __restrict__ nlist, const int* __restrict__ batch,
                        const float* __restrict__ dinv, const float* __restrict__ h2s,
                        const float* __restrict__ b2, float* __restrict__ out) {
    int i = threadIdx.x;
    if (i >= NGRAPH) return;
    int v = nlist[i];
    float di = dinv[v];
    out[batch[v]] += di * di * h2s[v] + b2[0];   // one big node per graph: race-free
}

extern "C" void kernel_launch(void* const* d_in, const int* in_sizes, int n_in,
                              void* d_out, int out_size, void* d_ws, size_t ws_size,
                              hipStream_t stream) {
    const float* x     = (const float*)d_in[0];
    const int*   eidx  = (const int*)d_in[1];
    const int*   src   = eidx;
    const int*   dst   = eidx + N_EDGES;
    const int*   batch = (const int*)d_in[2];
    const float* W1    = (const float*)d_in[3];
    const float* b1    = (const float*)d_in[4];
    const float* W2    = (const float*)d_in[5];
    const float* b2    = (const float*)d_in[6];
    float*       out   = (float*)d_out;

    // ---- workspace layout (zeroed region first: agg1 | deg | counters) ----
    char* ws = (char*)d_ws;
    size_t off = 0;
    float* agg1     = (float*)(ws + off); off += (size_t)N_NODES * HID * 4; // 25.6 MB
    int*   deg      = (int*)  (ws + off); off += (size_t)N_NODES * 4;       // 0.4 MB
    int*   counters = (int*)  (ws + off); off += 256;
    size_t zero_bytes = off;
    float* h_pre    = (float*)(ws + off); off += (size_t)N_NODES * HID * 4; // 25.6 MB
    float* dinv     = (float*)(ws + off); off += (size_t)N_NODES * 4;
    float* h2s      = (float*)(ws + off); off += (size_t)N_NODES * 4;
    int*   needed   = (int*)  (ws + off); off += (size_t)N_NODES * 4;
    int*   nlist    = (int*)  (ws + off); off += (size_t)NLCAP * 4;
    int2*  l1list   = (int2*) (ws + off); off += (size_t)L1CAP * 8;
    int2*  l2list   = (int2*) (ws + off); off += (size_t)L2CAP * 8;
    if (off > ws_size) return;  // visible validation failure if ws too small

    hipMemsetAsync(d_ws, 0, zero_bytes, stream);
    hipMemsetAsync(d_out, 0, (size_t)out_size * 4, stream);

    const int BN = (N_NODES + 255) / 256;

    k_init<<<BN, 256, 0, stream>>>(batch, needed, nlist, counters);
    k_degmark<<<1024, 256, 0, stream>>>(src, dst, batch, deg, needed, nlist, l2list, counters);
    k_compact1<<<1024, 256, 0, stream>>>(src, dst, needed, l1list, counters);
    k_dinv<<<BN, 256, 0, stream>>>(deg, dinv);
    k_gemm<<<2048, 256, 0, stream>>>(x, W1, h_pre);
    k_agg1<<<1024, 256, 0, stream>>>(l1list, counters, dinv, h_pre, agg1);
    k_node2<<<64, 256, 0, stream>>>(nlist, counters, agg1, h_pre, dinv, b1, W2, h2s);
    k_agg2<<<8, 256, 0, stream>>>(l2list, counters, dinv, h2s, batch, out);
    k_final<<<1, 64, 0, stream>>>(nlist, batch, dinv, h2s, b2, out);
}

// Round 3
// 314.660 us; speedup vs baseline: 2.7167x; 1.3489x over previous
//
#include <hip/hip_runtime.h>

#define N_NODES 100000
#define N_EDGES 3200000
#define F_IN    128
#define HID     64
#define NGRAPH  64

#define NBUK    196        // ceil(100000 / 512) buckets of 512 nodes
#define BSHIFT  9
#define BCAP    18432      // mean 16384, sigma ~128 -> +16 sigma
#define CHUNK   5120       // 256 threads x 20; 625 * 5120 == 3.2M exactly
#define NBLK_A  625
#define NWORDS  3200       // 100000 bits -> 3125 words, padded to x256
#define MAXDEG  96         // in-degree ~Poisson(32); P(>96) ~ 1e-19
#define NIDCAP  4096       // needed nodes ~2100
#define L2CAP   8192       // big-dst edges ~2048

// counters: [1]=l2 edge count, [2]=needed-node (nid) count

__device__ __forceinline__ bool is_big(int v, const int* __restrict__ batch) {
    return (v == N_NODES - 1) || (batch[v] != batch[v + 1]);
}

// Big nodes: set bigmask+nmask bits, assign nids 0..63, fill nlist/nid_of.
__global__ void k_init(const int* __restrict__ batch, unsigned* __restrict__ bigmask,
                       unsigned* __restrict__ nmask, int* __restrict__ nid_of,
                       int* __restrict__ nlist, int* __restrict__ counters) {
    int v = blockIdx.x * 256 + threadIdx.x;
    if (v >= N_NODES) return;
    if (is_big(v, batch)) {
        atomicOr(&bigmask[v >> 5], 1u << (v & 31));
        atomicOr(&nmask[v >> 5], 1u << (v & 31));
        int p = atomicAdd(&counters[2], 1);          // exactly 64
        nid_of[v] = p;
        nlist[p]  = v;
    }
}

// Pass A: partition dst[] into 196 node-range buckets (count -> reserve -> scatter,
// values stashed in registers). Fused: big-dst detection via LDS bigmask ->
// mark src in nmask, append (src,dst) to l2list (LDS-buffered, 1 flush/block).
__global__ __launch_bounds__(256) void k_partA(const int* __restrict__ src,
        const int* __restrict__ dst, const unsigned* __restrict__ bigmask,
        unsigned* __restrict__ nmask, int* __restrict__ plist,
        int* __restrict__ bcnt, int2* __restrict__ l2list, int* __restrict__ counters) {
    __shared__ unsigned bigm[NWORDS];                // 12.8 KB
    __shared__ int hist[NBUK], base_[NBUK], cur[NBUK];
    __shared__ int2 l2buf[64];
    __shared__ int l2n, l2base;
    for (int i = threadIdx.x; i < NWORDS; i += 256) bigm[i] = bigmask[i];
    for (int i = threadIdx.x; i < NBUK; i += 256) hist[i] = 0;
    if (threadIdx.x == 0) l2n = 0;
    __syncthreads();

    const int e0 = blockIdx.x * CHUNK + threadIdx.x;
    int vs[20];
#pragma unroll
    for (int it = 0; it < 20; ++it) {
        int e = e0 + it * 256;
        int v = dst[e];
        vs[it] = v;
        atomicAdd(&hist[v >> BSHIFT], 1);
        if ((bigm[v >> 5] >> (v & 31)) & 1) {
            int u = src[e];
            atomicOr(&nmask[u >> 5], 1u << (u & 31));   // ~2k total, scattered
            int p = atomicAdd(&l2n, 1);
            if (p < 64) l2buf[p] = make_int2(u, v);
        }
    }
    __syncthreads();
    for (int i = threadIdx.x; i < NBUK; i += 256) {
        base_[i] = atomicAdd(&bcnt[i], hist[i]);
        cur[i] = 0;
    }
    if (threadIdx.x == 0 && l2n > 0)
        l2base = atomicAdd(&counters[1], (l2n < 64 ? l2n : 64));
    __syncthreads();
    for (int i = threadIdx.x; i < l2n && i < 64; i += 256) {
        int p = l2base + i;
        if (p < L2CAP) l2list[p] = l2buf[i];
    }
#pragma unroll
    for (int it = 0; it < 20; ++it) {
        int v = vs[it];
        int b = v >> BSHIFT;
        int s = base_[b] + atomicAdd(&cur[b], 1);
        if (s < BCAP) plist[(size_t)b * BCAP + s] = v;
    }
}

// Assign nids to needed-but-not-big nodes: popcount + block scan, 1 atomic/block.
__global__ void k_buildnid(const unsigned* __restrict__ nmask,
                           const unsigned* __restrict__ bigmask,
                           int* __restrict__ nid_of, int* __restrict__ nlist,
                           int* __restrict__ counters) {
    int w = blockIdx.x * 256 + threadIdx.x;
    unsigned m = (w < NWORDS) ? (nmask[w] & ~bigmask[w]) : 0u;
    int c = __popc(m);
    __shared__ int sc[256];
    __shared__ int gbase;
    sc[threadIdx.x] = c;
    __syncthreads();
    for (int off = 1; off < 256; off <<= 1) {
        int t = (threadIdx.x >= off) ? sc[threadIdx.x - off] : 0;
        __syncthreads();
        sc[threadIdx.x] += t;
        __syncthreads();
    }
    if (threadIdx.x == 0) gbase = atomicAdd(&counters[2], sc[255]);
    __syncthreads();
    int p = gbase + sc[threadIdx.x] - c;             // exclusive offset
    while (m) {
        int b = __ffs(m) - 1; m &= m - 1;
        int v = w * 32 + b;
        if (p < NIDCAP) { nid_of[v] = p; nlist[p] = v; }
        p++;
    }
}

// Pass B: per-bucket 512-bin LDS histogram -> dinv (deg+1 self-loop). No global deg.
__global__ __launch_bounds__(256) void k_partB(const int* __restrict__ plist,
        const int* __restrict__ bcnt, float* __restrict__ dinv) {
    __shared__ int bins[512];
    for (int i = threadIdx.x; i < 512; i += 256) bins[i] = 0;
    __syncthreads();
    int b = blockIdx.x;
    int n = bcnt[b]; if (n > BCAP) n = BCAP;
    const int* lp = plist + (size_t)b * BCAP;
    int lo = b << BSHIFT;
    for (int i = threadIdx.x; i < n; i += 256) atomicAdd(&bins[lp[i] - lo], 1);
    __syncthreads();
    for (int i = threadIdx.x; i < 512; i += 256) {
        int v = lo + i;
        if (v < N_NODES) dinv[v] = rsqrtf((float)(bins[i] + 1));
    }
}

// h_pre = x @ W1 (N x 128 @ 128 x 64). W1 in LDS; wave = row, lane = feature.
__global__ __launch_bounds__(256) void k_gemm(const float* __restrict__ x,
                                              const float* __restrict__ W1,
                                              float* __restrict__ h_pre) {
    __shared__ float Wl[F_IN * HID];   // 32 KiB
    for (int i = threadIdx.x; i < F_IN * HID; i += 256) Wl[i] = W1[i];
    __syncthreads();
    int wave = threadIdx.x >> 6;
    int f    = threadIdx.x & 63;
    for (int v0 = blockIdx.x * 4; v0 < N_NODES; v0 += gridDim.x * 4) {
        int v = v0 + wave;
        if (v >= N_NODES) continue;
        const float4* xr = (const float4*)(x + (size_t)v * F_IN);
        float acc = 0.f;
#pragma unroll
        for (int k4 = 0; k4 < F_IN / 4; ++k4) {
            float4 xa = xr[k4];           // wave-broadcast load
            int k = k4 * 4;
            acc += xa.x * Wl[(k + 0) * HID + f];
            acc += xa.y * Wl[(k + 1) * HID + f];
            acc += xa.z * Wl[(k + 2) * HID + f];
            acc += xa.w * Wl[(k + 3) * HID + f];
        }
        h_pre[(size_t)v * HID + f] = acc;
    }
}

// CSR build: edges whose dst is needed -> csr[nid][slot] = src. LDS nmask check.
__global__ __launch_bounds__(256) void k_csr(const int* __restrict__ src,
        const int* __restrict__ dst, const unsigned* __restrict__ nmask,
        const int* __restrict__ nid_of, int* __restrict__ incnt,
        int* __restrict__ csr) {
    __shared__ unsigned nm[NWORDS];
    for (int i = threadIdx.x; i < NWORDS; i += 256) nm[i] = nmask[i];
    __syncthreads();
    const int e0 = blockIdx.x * CHUNK + threadIdx.x;
#pragma unroll
    for (int it = 0; it < 20; ++it) {
        int e = e0 + it * 256;
        int v = dst[e];
        if ((nm[v >> 5] >> (v & 31)) & 1) {
            int nid = nid_of[v];
            int slot = atomicAdd(&incnt[nid], 1);     // ~67k over ~2.1k counters
            if (slot < MAXDEG) csr[nid * MAXDEG + slot] = src[e];
        }
    }
}

// Fused layer-1 aggregation + bias/ReLU + W2 dot: one block per needed node.
// No atomics: register accumulation, 4 waves split the in-edges, LDS combine.
__global__ __launch_bounds__(256) void k_fusedagg(const int* __restrict__ nlist,
        const int* __restrict__ incnt, const int* __restrict__ csr,
        const float* __restrict__ dinv, const float* __restrict__ h_pre,
        const float* __restrict__ b1, const float* __restrict__ W2,
        const int* __restrict__ counters, float* __restrict__ h2s) {
    __shared__ float part[4 * HID];
    int ncnt = counters[2]; if (ncnt > NIDCAP) ncnt = NIDCAP;
    int f = threadIdx.x & 63, wid = threadIdx.x >> 6;
    for (int nid = blockIdx.x; nid < ncnt; nid += gridDim.x) {
        int v = nlist[nid];
        int m = incnt[nid]; if (m > MAXDEG) m = MAXDEG;
        float dv = dinv[v];
        float acc = 0.f;
        const int* cs = csr + nid * MAXDEG;
#pragma unroll 2
        for (int j = wid; j < m; j += 4) {
            int u = cs[j];                              // wave-broadcast
            acc += dinv[u] * h_pre[(size_t)u * HID + f]; // coalesced 256B row
        }
        part[wid * HID + f] = acc;
        __syncthreads();
        if (wid == 0) {
            float s = part[f] + part[HID + f] + part[2 * HID + f] + part[3 * HID + f];
            float val = s * dv + dv * dv * h_pre[(size_t)v * HID + f] + b1[f];
            val = fmaxf(val, 0.f);
            float c = val * W2[f];
#pragma unroll
            for (int off = 32; off > 0; off >>= 1) c += __shfl_down(c, off, 64);
            if (f == 0) h2s[v] = c;
        }
        __syncthreads();
    }
}

// layer-2 aggregation over ~2k big-dst edges
__global__ void k_agg2(const int2* __restrict__ l2list, const int* __restrict__ counters,
                       const float* __restrict__ dinv, const float* __restrict__ h2s,
                       const int* __restrict__ batch, float* __restrict__ out) {
    int tid = blockIdx.x * 256 + threadIdx.x;
    int nt  = gridDim.x * 256;
    int n   = counters[1];
    if (n > L2CAP) n = L2CAP;
    for (int i = tid; i < n; i += nt) {
        int2 e = l2list[i];
        atomicAdd(&out[batch[e.y]], dinv[e.x] * dinv[e.y] * h2s[e.x]);
    }
}

// self-loop + b2 per big node; nlist[0..63] are exactly the big nodes (k_init)
__global__ void k_final(const int* __restrict__ nlist, const int* __restrict__ batch,
                        const float* __restrict__ dinv, const float* __restrict__ h2s,
                        const float* __restrict__ b2, float* __restrict__ out) {
    int i = threadIdx.x;
    if (i >= NGRAPH) return;
    int v = nlist[i];
    float di = dinv[v];
    out[batch[v]] += di * di * h2s[v] + b2[0];
}

extern "C" void kernel_launch(void* const* d_in, const int* in_sizes, int n_in,
                              void* d_out, int out_size, void* d_ws, size_t ws_size,
                              hipStream_t stream) {
    const float* x     = (const float*)d_in[0];
    const int*   eidx  = (const int*)d_in[1];
    const int*   src   = eidx;
    const int*   dst   = eidx + N_EDGES;
    const int*   batch = (const int*)d_in[2];
    const float* W1    = (const float*)d_in[3];
    const float* b1    = (const float*)d_in[4];
    const float* W2    = (const float*)d_in[5];
    const float* b2    = (const float*)d_in[6];
    float*       out   = (float*)d_out;

    // ---- workspace layout: zeroed region first ----
    char* ws = (char*)d_ws;
    size_t off = 0;
    int*      counters = (int*)(ws + off);      off += 256;
    int*      bcnt     = (int*)(ws + off);      off += 1024;               // NBUK*4 padded
    unsigned* nmask    = (unsigned*)(ws + off); off += NWORDS * 4;         // 12.8 KB
    unsigned* bigmask  = (unsigned*)(ws + off); off += NWORDS * 4;
    int*      incnt    = (int*)(ws + off);      off += NIDCAP * 4;         // 16 KB
    size_t zero_bytes = off;                                               // ~43 KB
    float*    h_pre    = (float*)(ws + off);    off += (size_t)N_NODES * HID * 4; // 25.6 MB
    float*    dinv     = (float*)(ws + off);    off += (size_t)N_NODES * 4;
    float*    h2s      = (float*)(ws + off);    off += (size_t)N_NODES * 4;
    int*      nid_of   = (int*)(ws + off);      off += (size_t)N_NODES * 4;
    int*      nlist    = (int*)(ws + off);      off += (size_t)NIDCAP * 4;
    int2*     l2list   = (int2*)(ws + off);     off += (size_t)L2CAP * 8;
    int*      csr      = (int*)(ws + off);      off += (size_t)NIDCAP * MAXDEG * 4; // 1.6 MB
    int*      plist    = (int*)(ws + off);      off += (size_t)NBUK * BCAP * 4;     // 14.5 MB
    if (off > ws_size) return;  // visible validation failure if ws too small

    hipMemsetAsync(d_ws, 0, zero_bytes, stream);
    hipMemsetAsync(d_out, 0, (size_t)out_size * 4, stream);

    const int BN = (N_NODES + 255) / 256;

    k_init<<<BN, 256, 0, stream>>>(batch, bigmask, nmask, nid_of, nlist, counters);
    k_partA<<<NBLK_A, 256, 0, stream>>>(src, dst, bigmask, nmask, plist, bcnt, l2list, counters);
    k_buildnid<<<(NWORDS + 255) / 256, 256, 0, stream>>>(nmask, bigmask, nid_of, nlist, counters);
    k_partB<<<NBUK, 256, 0, stream>>>(plist, bcnt, dinv);
    k_gemm<<<2048, 256, 0, stream>>>(x, W1, h_pre);
    k_csr<<<NBLK_A, 256, 0, stream>>>(src, dst, nmask, nid_of, incnt, csr);
    k_fusedagg<<<2048, 256, 0, stream>>>(nlist, incnt, csr, dinv, h_pre, b1, W2, counters, h2s);
    k_agg2<<<8, 256, 0, stream>>>(l2list, counters, dinv, h2s, batch, out);
    k_final<<<1, 64, 0, stream>>>(nlist, batch, dinv, h2s, b2, out);
}

// Round 4
// 237.888 us; speedup vs baseline: 3.5934x; 1.3227x over previous
//
#include <hip/hip_runtime.h>

#define N_NODES 100000
#define N_EDGES 3200000
#define F_IN    128
#define HID     64
#define NGRAPH  64

#define NBUK    196        // ceil(100000 / 512) buckets of 512 nodes
#define BSHIFT  9
#define BCAP    18432      // mean 16384, sigma ~128 -> +16 sigma
#define CHUNK   5120       // 256 threads x 20; 625 * 5120 == 3.2M exactly
#define NBLK_A  625
#define NWORDS  3200       // 100000 bits -> 3125 words, padded to x256
#define MAXDEG  96         // in-degree ~Poisson(32); P(>96) ~ 1e-19
#define NIDCAP  4096       // needed nodes ~2100
#define L2CAP   8192       // big-dst edges ~2048

// counters: [1]=l2 edge count, [2]=needed-node (nid) count

__device__ __forceinline__ bool is_big(int v, const int* __restrict__ batch) {
    return (v == N_NODES - 1) || (batch[v] != batch[v + 1]);
}

// Big nodes: set bigmask+nmask bits, assign nids 0..63, fill nlist/nid_of.
__global__ void k_init(const int* __restrict__ batch, unsigned* __restrict__ bigmask,
                       unsigned* __restrict__ nmask, int* __restrict__ nid_of,
                       int* __restrict__ nlist, int* __restrict__ counters) {
    int v = blockIdx.x * 256 + threadIdx.x;
    if (v >= N_NODES) return;
    if (is_big(v, batch)) {
        atomicOr(&bigmask[v >> 5], 1u << (v & 31));
        atomicOr(&nmask[v >> 5], 1u << (v & 31));
        int p = atomicAdd(&counters[2], 1);          // exactly 64
        nid_of[v] = p;
        nlist[p]  = v;
    }
}

// Pass A: partition dst[] into 196 node-range buckets (count -> reserve -> scatter,
// values stashed in registers; ushort bucket-local payload). Fused: big-dst
// detection via LDS bigmask -> mark src in nmask, append to l2list.
__global__ __launch_bounds__(256) void k_partA(const int* __restrict__ src,
        const int* __restrict__ dst, const unsigned* __restrict__ bigmask,
        unsigned* __restrict__ nmask, unsigned short* __restrict__ plist,
        int* __restrict__ bcnt, int2* __restrict__ l2list, int* __restrict__ counters) {
    __shared__ unsigned bigm[NWORDS];                // 12.8 KB
    __shared__ int hist[NBUK], base_[NBUK], cur[NBUK];
    __shared__ int2 l2buf[64];
    __shared__ int l2n, l2base;
    for (int i = threadIdx.x; i < NWORDS; i += 256) bigm[i] = bigmask[i];
    for (int i = threadIdx.x; i < NBUK; i += 256) hist[i] = 0;
    if (threadIdx.x == 0) l2n = 0;
    __syncthreads();

    const int e0 = blockIdx.x * CHUNK + threadIdx.x;
    int vs[20];
#pragma unroll
    for (int it = 0; it < 20; ++it) {
        int e = e0 + it * 256;
        int v = dst[e];
        vs[it] = v;
        atomicAdd(&hist[v >> BSHIFT], 1);
        if ((bigm[v >> 5] >> (v & 31)) & 1) {
            int u = src[e];
            atomicOr(&nmask[u >> 5], 1u << (u & 31));   // ~2k total, scattered
            int p = atomicAdd(&l2n, 1);
            if (p < 64) l2buf[p] = make_int2(u, v);
        }
    }
    __syncthreads();
    for (int i = threadIdx.x; i < NBUK; i += 256) {
        base_[i] = atomicAdd(&bcnt[i], hist[i]);
        cur[i] = 0;
    }
    if (threadIdx.x == 0 && l2n > 0)
        l2base = atomicAdd(&counters[1], (l2n < 64 ? l2n : 64));
    __syncthreads();
    for (int i = threadIdx.x; i < l2n && i < 64; i += 256) {
        int p = l2base + i;
        if (p < L2CAP) l2list[p] = l2buf[i];
    }
#pragma unroll
    for (int it = 0; it < 20; ++it) {
        int v = vs[it];
        int b = v >> BSHIFT;
        int s = base_[b] + atomicAdd(&cur[b], 1);
        if (s < BCAP) plist[(size_t)b * BCAP + s] = (unsigned short)(v & 511);
    }
}

// Assign nids to needed-but-not-big nodes: popcount + block scan, 1 atomic/block.
__global__ void k_buildnid(const unsigned* __restrict__ nmask,
                           const unsigned* __restrict__ bigmask,
                           int* __restrict__ nid_of, int* __restrict__ nlist,
                           int* __restrict__ counters) {
    int w = blockIdx.x * 256 + threadIdx.x;
    unsigned m = (w < NWORDS) ? (nmask[w] & ~bigmask[w]) : 0u;
    int c = __popc(m);
    __shared__ int sc[256];
    __shared__ int gbase;
    sc[threadIdx.x] = c;
    __syncthreads();
    for (int off = 1; off < 256; off <<= 1) {
        int t = (threadIdx.x >= off) ? sc[threadIdx.x - off] : 0;
        __syncthreads();
        sc[threadIdx.x] += t;
        __syncthreads();
    }
    if (threadIdx.x == 0) gbase = atomicAdd(&counters[2], sc[255]);
    __syncthreads();
    int p = gbase + sc[threadIdx.x] - c;             // exclusive offset
    while (m) {
        int b = __ffs(m) - 1; m &= m - 1;
        int v = w * 32 + b;
        if (p < NIDCAP) { nid_of[v] = p; nlist[p] = v; }
        p++;
    }
}

// Pass B: per-bucket 512-bin LDS histogram -> dinv (deg+1 self-loop).
__global__ __launch_bounds__(256) void k_partB(const unsigned short* __restrict__ plist,
        const int* __restrict__ bcnt, float* __restrict__ dinv) {
    __shared__ int bins[512];
    for (int i = threadIdx.x; i < 512; i += 256) bins[i] = 0;
    __syncthreads();
    int b = blockIdx.x;
    int n = bcnt[b]; if (n > BCAP) n = BCAP;
    const unsigned short* lp = plist + (size_t)b * BCAP;
    int lo = b << BSHIFT;
    for (int i = threadIdx.x; i < n; i += 256) atomicAdd(&bins[lp[i]], 1);
    __syncthreads();
    for (int i = threadIdx.x; i < 512; i += 256) {
        int v = lo + i;
        if (v < N_NODES) dinv[v] = rsqrtf((float)(bins[i] + 1));
    }
}

// h_pre = x @ W1 (N x 128 @ 128 x 64). Register-tiled SGEMM:
// block = 64 rows x 64 cols, thread (ty,tx) owns 4x4. K in two 64-chunks.
// xs padded to ld 65 -> per-k row reads hit 4 distinct banks, 16-lane broadcast.
__global__ __launch_bounds__(256) void k_gemm(const float* __restrict__ x,
                                              const float* __restrict__ W1,
                                              float* __restrict__ h_pre) {
    __shared__ float xs[64 * 65];      // [row][klocal], ld 65 (16.6 KB)
    __shared__ float Ws[64 * 64];      // [klocal][col]   (16 KB)
    const int tid = threadIdx.x;
    const int ty = tid >> 4, tx = tid & 15;
    const int R0 = blockIdx.x * 64;
    float acc[4][4] = {};
#pragma unroll
    for (int kc = 0; kc < 2; ++kc) {
        int idx = tid;
#pragma unroll
        for (int p = 0; p < 4; ++p, idx += 256) {     // x tile: 64 rows x 16 float4
            int r = idx >> 4, k4 = idx & 15;
            int row = R0 + r;
            float4 v = make_float4(0.f, 0.f, 0.f, 0.f);
            if (row < N_NODES)
                v = *(const float4*)(x + (size_t)row * F_IN + kc * 64 + 4 * k4);
            float* d = xs + r * 65 + 4 * k4;          // 4B-aligned: scalar stores
            d[0] = v.x; d[1] = v.y; d[2] = v.z; d[3] = v.w;
        }
        idx = tid;
#pragma unroll
        for (int p = 0; p < 4; ++p, idx += 256) {     // W tile: 64 k x 16 float4
            int kl = idx >> 4, c4 = idx & 15;
            *(float4*)(Ws + kl * 64 + 4 * c4) =
                *(const float4*)(W1 + (size_t)(kc * 64 + kl) * HID + 4 * c4);
        }
        __syncthreads();
#pragma unroll 4
        for (int k = 0; k < 64; ++k) {
            float4 b = *(const float4*)(Ws + k * 64 + 4 * tx);  // 4-way broadcast
            float a0 = xs[(4 * ty + 0) * 65 + k];               // 16-way broadcast
            float a1 = xs[(4 * ty + 1) * 65 + k];
            float a2 = xs[(4 * ty + 2) * 65 + k];
            float a3 = xs[(4 * ty + 3) * 65 + k];
            acc[0][0] += a0 * b.x; acc[0][1] += a0 * b.y; acc[0][2] += a0 * b.z; acc[0][3] += a0 * b.w;
            acc[1][0] += a1 * b.x; acc[1][1] += a1 * b.y; acc[1][2] += a1 * b.z; acc[1][3] += a1 * b.w;
            acc[2][0] += a2 * b.x; acc[2][1] += a2 * b.y; acc[2][2] += a2 * b.z; acc[2][3] += a2 * b.w;
            acc[3][0] += a3 * b.x; acc[3][1] += a3 * b.y; acc[3][2] += a3 * b.z; acc[3][3] += a3 * b.w;
        }
        __syncthreads();
    }
#pragma unroll
    for (int i = 0; i < 4; ++i) {
        int row = R0 + 4 * ty + i;
        if (row < N_NODES)
            *(float4*)(h_pre + (size_t)row * HID + 4 * tx) =
                make_float4(acc[i][0], acc[i][1], acc[i][2], acc[i][3]);
    }
}

// CSR build: edges whose dst is needed -> csr[nid][slot] = src. LDS nmask check.
__global__ __launch_bounds__(256) void k_csr(const int* __restrict__ src,
        const int* __restrict__ dst, const unsigned* __restrict__ nmask,
        const int* __restrict__ nid_of, int* __restrict__ incnt,
        int* __restrict__ csr) {
    __shared__ unsigned nm[NWORDS];
    for (int i = threadIdx.x; i < NWORDS; i += 256) nm[i] = nmask[i];
    __syncthreads();
    const int e0 = blockIdx.x * CHUNK + threadIdx.x;
#pragma unroll
    for (int it = 0; it < 20; ++it) {
        int e = e0 + it * 256;
        int v = dst[e];
        if ((nm[v >> 5] >> (v & 31)) & 1) {
            int nid = nid_of[v];
            int slot = atomicAdd(&incnt[nid], 1);     // ~67k over ~2.1k counters
            if (slot < MAXDEG) csr[nid * MAXDEG + slot] = src[e];
        }
    }
}

// Fused layer-1 aggregation + bias/ReLU + W2 dot: one block per needed node.
__global__ __launch_bounds__(256) void k_fusedagg(const int* __restrict__ nlist,
        const int* __restrict__ incnt, const int* __restrict__ csr,
        const float* __restrict__ dinv, const float* __restrict__ h_pre,
        const float* __restrict__ b1, const float* __restrict__ W2,
        const int* __restrict__ counters, float* __restrict__ h2s) {
    __shared__ float part[4 * HID];
    int ncnt = counters[2]; if (ncnt > NIDCAP) ncnt = NIDCAP;
    int f = threadIdx.x & 63, wid = threadIdx.x >> 6;
    for (int nid = blockIdx.x; nid < ncnt; nid += gridDim.x) {
        int v = nlist[nid];
        int m = incnt[nid]; if (m > MAXDEG) m = MAXDEG;
        float dv = dinv[v];
        float acc = 0.f;
        const int* cs = csr + nid * MAXDEG;
#pragma unroll 2
        for (int j = wid; j < m; j += 4) {
            int u = cs[j];                               // wave-broadcast
            acc += dinv[u] * h_pre[(size_t)u * HID + f]; // coalesced 256B row
        }
        part[wid * HID + f] = acc;
        __syncthreads();
        if (wid == 0) {
            float s = part[f] + part[HID + f] + part[2 * HID + f] + part[3 * HID + f];
            float val = s * dv + dv * dv * h_pre[(size_t)v * HID + f] + b1[f];
            val = fmaxf(val, 0.f);
            float c = val * W2[f];
#pragma unroll
            for (int off = 32; off > 0; off >>= 1) c += __shfl_down(c, off, 64);
            if (f == 0) h2s[v] = c;
        }
        __syncthreads();
    }
}

// layer-2 aggregation over ~2k big-dst edges
__global__ void k_agg2(const int2* __restrict__ l2list, const int* __restrict__ counters,
                       const float* __restrict__ dinv, const float* __restrict__ h2s,
                       const int* __restrict__ batch, float* __restrict__ out) {
    int tid = blockIdx.x * 256 + threadIdx.x;
    int nt  = gridDim.x * 256;
    int n   = counters[1];
    if (n > L2CAP) n = L2CAP;
    for (int i = tid; i < n; i += nt) {
        int2 e = l2list[i];
        atomicAdd(&out[batch[e.y]], dinv[e.x] * dinv[e.y] * h2s[e.x]);
    }
}

// self-loop + b2 per big node; nlist[0..63] are exactly the big nodes (k_init)
__global__ void k_final(const int* __restrict__ nlist, const int* __restrict__ batch,
                        const float* __restrict__ dinv, const float* __restrict__ h2s,
                        const float* __restrict__ b2, float* __restrict__ out) {
    int i = threadIdx.x;
    if (i >= NGRAPH) return;
    int v = nlist[i];
    float di = dinv[v];
    out[batch[v]] += di * di * h2s[v] + b2[0];
}

extern "C" void kernel_launch(void* const* d_in, const int* in_sizes, int n_in,
                              void* d_out, int out_size, void* d_ws, size_t ws_size,
                              hipStream_t stream) {
    const float* x     = (const float*)d_in[0];
    const int*   eidx  = (const int*)d_in[1];
    const int*   src   = eidx;
    const int*   dst   = eidx + N_EDGES;
    const int*   batch = (const int*)d_in[2];
    const float* W1    = (const float*)d_in[3];
    const float* b1    = (const float*)d_in[4];
    const float* W2    = (const float*)d_in[5];
    const float* b2    = (const float*)d_in[6];
    float*       out   = (float*)d_out;

    // ---- workspace layout: zeroed region first ----
    char* ws = (char*)d_ws;
    size_t off = 0;
    int*      counters = (int*)(ws + off);      off += 256;
    int*      bcnt     = (int*)(ws + off);      off += 1024;               // NBUK*4 padded
    unsigned* nmask    = (unsigned*)(ws + off); off += NWORDS * 4;         // 12.8 KB
    unsigned* bigmask  = (unsigned*)(ws + off); off += NWORDS * 4;
    int*      incnt    = (int*)(ws + off);      off += NIDCAP * 4;         // 16 KB
    size_t zero_bytes = off;                                               // ~43 KB
    float*    h_pre    = (float*)(ws + off);    off += (size_t)N_NODES * HID * 4; // 25.6 MB
    float*    dinv     = (float*)(ws + off);    off += (size_t)N_NODES * 4;
    float*    h2s      = (float*)(ws + off);    off += (size_t)N_NODES * 4;
    int*      nid_of   = (int*)(ws + off);      off += (size_t)N_NODES * 4;
    int*      nlist    = (int*)(ws + off);      off += (size_t)NIDCAP * 4;
    int2*     l2list   = (int2*)(ws + off);     off += (size_t)L2CAP * 8;
    int*      csr      = (int*)(ws + off);      off += (size_t)NIDCAP * MAXDEG * 4; // 1.6 MB
    unsigned short* plist = (unsigned short*)(ws + off); off += (size_t)NBUK * BCAP * 2; // 7.2 MB
    if (off > ws_size) return;  // visible validation failure if ws too small

    hipMemsetAsync(d_ws, 0, zero_bytes, stream);
    hipMemsetAsync(d_out, 0, (size_t)out_size * 4, stream);

    const int BN = (N_NODES + 255) / 256;

    k_init<<<BN, 256, 0, stream>>>(batch, bigmask, nmask, nid_of, nlist, counters);
    k_partA<<<NBLK_A, 256, 0, stream>>>(src, dst, bigmask, nmask, plist, bcnt, l2list, counters);
    k_buildnid<<<(NWORDS + 255) / 256, 256, 0, stream>>>(nmask, bigmask, nid_of, nlist, counters);
    k_partB<<<NBUK, 256, 0, stream>>>(plist, bcnt, dinv);
    k_gemm<<<(N_NODES + 63) / 64, 256, 0, stream>>>(x, W1, h_pre);
    k_csr<<<NBLK_A, 256, 0, stream>>>(src, dst, nmask, nid_of, incnt, csr);
    k_fusedagg<<<2048, 256, 0, stream>>>(nlist, incnt, csr, dinv, h_pre, b1, W2, counters, h2s);
    k_agg2<<<8, 256, 0, stream>>>(l2list, counters, dinv, h2s, batch, out);
    k_final<<<1, 64, 0, stream>>>(nlist, batch, dinv, h2s, b2, out);
}